// Round 6
// baseline (268.873 us; speedup 1.0000x reference)
//
#include <hip/hip_runtime.h>

// predictions [16,12,512,512] f32, targets [16,512,512] int32.
// out = mean over B*C*H*W of (pred[b,c,h,w] - (c <= t[b,h,w]))^2.

constexpr int BATCH    = 16;
constexpr int NCLS     = 12;
constexpr int HW       = 512 * 512;              // 2^18
constexpr int NPIX     = BATCH * HW;             // 4,194,304
constexpr int NBLOCKS  = 2048;
constexpr int NTHREADS = 256;
// 2048*256 = 524,288 threads * 8 pixels/thread = 4,194,304 = NPIX exactly.

// Native clang vectors — __builtin_nontemporal_load requires these, not
// HIP_vector_type structs.
typedef float v4f __attribute__((ext_vector_type(4)));
typedef int   v4i __attribute__((ext_vector_type(4)));

__global__ __launch_bounds__(NTHREADS) void ord_partial_kernel(
        const float* __restrict__ pred,
        const int*   __restrict__ tgt,
        float*       __restrict__ partial) {
    const int tid = blockIdx.x * NTHREADS + threadIdx.x;

    // 8 consecutive pixels per thread, single pass: wave reads 2 KB
    // contiguous per class plane (2 back-to-back dwordx4 per lane).
    const int p8 = tid << 3;               // first pixel
    const int b  = p8 >> 18;               // p8 / HW (8-pixel run never straddles batch)
    const int hw = p8 & (HW - 1);          // p8 % HW

    const v4i t0 = __builtin_nontemporal_load(reinterpret_cast<const v4i*>(tgt + p8));
    const v4i t1 = __builtin_nontemporal_load(reinterpret_cast<const v4i*>(tgt + p8 + 4));
    const float* base = pred + (size_t)b * (NCLS * HW) + hw;

    float acc = 0.0f;
    #pragma unroll
    for (int c = 0; c < NCLS; ++c) {
        const v4f va = __builtin_nontemporal_load(
            reinterpret_cast<const v4f*>(base + (size_t)c * HW));
        const v4f vb = __builtin_nontemporal_load(
            reinterpret_cast<const v4f*>(base + (size_t)c * HW + 4));
        const float d0 = va.x - ((c <= t0.x) ? 1.0f : 0.0f);
        const float d1 = va.y - ((c <= t0.y) ? 1.0f : 0.0f);
        const float d2 = va.z - ((c <= t0.z) ? 1.0f : 0.0f);
        const float d3 = va.w - ((c <= t0.w) ? 1.0f : 0.0f);
        const float d4 = vb.x - ((c <= t1.x) ? 1.0f : 0.0f);
        const float d5 = vb.y - ((c <= t1.y) ? 1.0f : 0.0f);
        const float d6 = vb.z - ((c <= t1.z) ? 1.0f : 0.0f);
        const float d7 = vb.w - ((c <= t1.w) ? 1.0f : 0.0f);
        acc = fmaf(d0, d0, acc);
        acc = fmaf(d1, d1, acc);
        acc = fmaf(d2, d2, acc);
        acc = fmaf(d3, d3, acc);
        acc = fmaf(d4, d4, acc);
        acc = fmaf(d5, d5, acc);
        acc = fmaf(d6, d6, acc);
        acc = fmaf(d7, d7, acc);
    }

    // 64-lane wave reduction
    #pragma unroll
    for (int off = 32; off > 0; off >>= 1)
        acc += __shfl_down(acc, off, 64);

    __shared__ float wsum[NTHREADS / 64];
    const int lane = threadIdx.x & 63;
    const int wid  = threadIdx.x >> 6;
    if (lane == 0) wsum[wid] = acc;
    __syncthreads();
    if (threadIdx.x == 0)
        partial[blockIdx.x] = wsum[0] + wsum[1] + wsum[2] + wsum[3];
}

__global__ __launch_bounds__(NTHREADS) void ord_final_kernel(
        const float* __restrict__ partial,
        float*       __restrict__ out) {
    double acc = 0.0;
    for (int i = threadIdx.x; i < NBLOCKS; i += NTHREADS)
        acc += (double)partial[i];

    #pragma unroll
    for (int off = 32; off > 0; off >>= 1)
        acc += __shfl_down(acc, off, 64);

    __shared__ double wsum[NTHREADS / 64];
    const int lane = threadIdx.x & 63;
    const int wid  = threadIdx.x >> 6;
    if (lane == 0) wsum[wid] = acc;
    __syncthreads();
    if (threadIdx.x == 0) {
        const double total = wsum[0] + wsum[1] + wsum[2] + wsum[3];
        out[0] = (float)(total / (double)((size_t)NPIX * NCLS));
    }
}

extern "C" void kernel_launch(void* const* d_in, const int* in_sizes, int n_in,
                              void* d_out, int out_size, void* d_ws, size_t ws_size,
                              hipStream_t stream) {
    const float* pred = (const float*)d_in[0];
    const int*   tgt  = (const int*)d_in[1];
    float* out        = (float*)d_out;
    float* partial    = (float*)d_ws;    // 2048 floats = 8 KB of the workspace

    ord_partial_kernel<<<NBLOCKS, NTHREADS, 0, stream>>>(pred, tgt, partial);
    ord_final_kernel<<<1, NTHREADS, 0, stream>>>(partial, out);
}